// Round 1
// baseline (1441.795 us; speedup 1.0000x reference)
//
#include <hip/hip_runtime.h>
#include <math.h>

static inline size_t align256(size_t x) { return (x + 255) & ~(size_t)255; }

// ---------------- degree histogram ----------------
__global__ __launch_bounds__(256) void k_hist(const int* __restrict__ esrc,
                                              const int* __restrict__ edst,
                                              int* __restrict__ cntOut,
                                              int* __restrict__ cntIn, int E) {
  int i = blockIdx.x * 256 + threadIdx.x;
  if (i < E) {
    atomicAdd(&cntOut[esrc[i]], 1);
    atomicAdd(&cntIn[edst[i]], 1);
  }
}

__global__ __launch_bounds__(256) void k_norms(const int* __restrict__ cntOut,
                                               const int* __restrict__ cntIn,
                                               float* __restrict__ normOut,
                                               float* __restrict__ normIn, int n) {
  int i = blockIdx.x * 256 + threadIdx.x;
  if (i < n) {
    normOut[i] = rsqrtf((float)max(cntOut[i], 1));
    normIn[i]  = rsqrtf((float)max(cntIn[i], 1));
  }
}

// ---------------- exclusive scan (3-phase) ----------------
__global__ __launch_bounds__(256) void k_scan1(const int* __restrict__ in,
                                               int* __restrict__ out,
                                               int* __restrict__ bsums, int n) {
  __shared__ int s[256];
  int tid = threadIdx.x, gid = blockIdx.x * 256 + tid;
  int v = (gid < n) ? in[gid] : 0;
  s[tid] = v; __syncthreads();
  for (int o = 1; o < 256; o <<= 1) {
    int t = (tid >= o) ? s[tid - o] : 0;
    __syncthreads();
    s[tid] += t;
    __syncthreads();
  }
  if (gid < n) out[gid] = s[tid] - v;   // exclusive
  if (tid == 255) bsums[blockIdx.x] = s[255];
}

__global__ __launch_bounds__(512) void k_scan2(int* __restrict__ bsums, int nb) {
  __shared__ int s[512];
  int tid = threadIdx.x;
  int v = (tid < nb) ? bsums[tid] : 0;
  s[tid] = v; __syncthreads();
  for (int o = 1; o < 512; o <<= 1) {
    int t = (tid >= o) ? s[tid - o] : 0;
    __syncthreads();
    s[tid] += t;
    __syncthreads();
  }
  if (tid < nb) bsums[tid] = s[tid] - v;  // exclusive
}

__global__ __launch_bounds__(256) void k_scan3(int* __restrict__ offs,
                                               const int* __restrict__ bsums,
                                               int* __restrict__ cursor, int n) {
  int gid = blockIdx.x * 256 + threadIdx.x;
  if (gid < n) {
    int v = offs[gid] + bsums[blockIdx.x];
    offs[gid] = v;
    cursor[gid] = v;
  }
}

__global__ __launch_bounds__(256) void k_scatter(const int* __restrict__ esrc,
                                                 const int* __restrict__ edst,
                                                 int* __restrict__ cursor,
                                                 int* __restrict__ csr, int E) {
  int i = blockIdx.x * 256 + threadIdx.x;
  if (i < E) {
    int p = atomicAdd(&cursor[edst[i]], 1);
    csr[p] = esrc[i];
  }
}

// ---------------- scaled GEMM: out[n x C] = diag(scale) * A[n x K] @ W[K x C] ----------------
template <int K, int C>
__global__ __launch_bounds__(256) void k_gemm(const float* __restrict__ A,
                                              const float* __restrict__ scale,
                                              const float* __restrict__ W,
                                              float* __restrict__ out, int n) {
  constexpr int ROWS = 32, KB = 64;
  constexpr int CG = C / 4;          // column groups of 4
  constexpr int RG = 256 / CG;       // row groups
  constexpr int RPT = ROWS / RG;     // rows per thread
  __shared__ __align__(16) float Wl[KB * C];
  __shared__ __align__(16) float Al[ROWS * KB];
  int tid = threadIdx.x;
  int r0 = blockIdx.x * ROWS;
  int cg = tid % CG, rg = tid / CG, c0 = cg * 4;
  float acc[RPT][4];
#pragma unroll
  for (int i = 0; i < RPT; ++i) { acc[i][0] = acc[i][1] = acc[i][2] = acc[i][3] = 0.f; }

  for (int kb = 0; kb < K; kb += KB) {
    for (int idx = tid; idx < KB * C; idx += 256)
      Wl[idx] = W[(size_t)kb * C + idx];
    for (int idx = tid; idx < ROWS * KB; idx += 256) {
      int row = idx / KB, k = idx % KB;
      int g = r0 + row;
      Al[idx] = (g < n) ? A[(size_t)g * K + kb + k] * scale[g] : 0.f;
    }
    __syncthreads();
    for (int k = 0; k < KB; ++k) {
      float4 w = *(const float4*)&Wl[k * C + c0];
#pragma unroll
      for (int i = 0; i < RPT; ++i) {
        float a = Al[(rg + i * RG) * KB + k];
        acc[i][0] += a * w.x; acc[i][1] += a * w.y;
        acc[i][2] += a * w.z; acc[i][3] += a * w.w;
      }
    }
    __syncthreads();
  }
#pragma unroll
  for (int i = 0; i < RPT; ++i) {
    int g = r0 + rg + i * RG;
    if (g < n)
      *(float4*)&out[(size_t)g * C + c0] =
          make_float4(acc[i][0], acc[i][1], acc[i][2], acc[i][3]);
  }
}

// ---------------- aggregation: one wave per dst node ----------------
__global__ __launch_bounds__(256) void k_agg128_relu(const float* __restrict__ X,
                                                     const int* __restrict__ csr,
                                                     const int* __restrict__ offs,
                                                     const int* __restrict__ cnt,
                                                     const float* __restrict__ norm,
                                                     const float* __restrict__ bias,
                                                     float* __restrict__ H, int n) {
  int wid = blockIdx.x * 4 + (threadIdx.x >> 6);
  if (wid >= n) return;
  int lane = threadIdx.x & 63;
  int start = offs[wid], m = cnt[wid];
  float ax = 0.f, ay = 0.f;
  for (int e = 0; e < m; ++e) {
    int s = csr[start + e];
    float2 v = *(const float2*)(X + (size_t)s * 128 + lane * 2);
    ax += v.x; ay += v.y;
  }
  float nm = norm[wid];
  float2 b = *(const float2*)(bias + lane * 2);
  float ox = fmaxf(ax * nm + b.x, 0.f);
  float oy = fmaxf(ay * nm + b.y, 0.f);
  *(float2*)(H + (size_t)wid * 128 + lane * 2) = make_float2(ox, oy);
}

__global__ __launch_bounds__(256) void k_agg64(const float* __restrict__ X,
                                               const int* __restrict__ csr,
                                               const int* __restrict__ offs,
                                               const int* __restrict__ cnt,
                                               const float* __restrict__ norm,
                                               const float* __restrict__ bias,
                                               float* __restrict__ H, int n) {
  int wid = blockIdx.x * 4 + (threadIdx.x >> 6);
  if (wid >= n) return;
  int lane = threadIdx.x & 63;
  int start = offs[wid], m = cnt[wid];
  float a = 0.f;
  for (int e = 0; e < m; ++e) {
    int s = csr[start + e];
    a += X[(size_t)s * 64 + lane];
  }
  H[(size_t)wid * 64 + lane] = a * norm[wid] + bias[lane];
}

// ---------------- edge scoring: 16 lanes per query ----------------
__global__ __launch_bounds__(256) void k_score(const float* __restrict__ H,
                                               const int* __restrict__ qs,
                                               const int* __restrict__ qd,
                                               float* __restrict__ out, int q) {
  int t = blockIdx.x * 256 + threadIdx.x;
  int sub = t & 15;
  int q0 = t >> 4;
  float p = 0.f;
  if (q0 < q) {
    int s = qs[q0], d = qd[q0];
    float4 a = *(const float4*)(H + (size_t)s * 64 + sub * 4);
    float4 b = *(const float4*)(H + (size_t)d * 64 + sub * 4);
    p = a.x * b.x + a.y * b.y + a.z * b.z + a.w * b.w;
  }
  p += __shfl_xor(p, 1);
  p += __shfl_xor(p, 2);
  p += __shfl_xor(p, 4);
  p += __shfl_xor(p, 8);
  if (sub == 0 && q0 < q) out[q0] = 1.f / (1.f + expf(-p));
}

extern "C" void kernel_launch(void* const* d_in, const int* in_sizes, int n_in,
                              void* d_out, int out_size, void* d_ws, size_t ws_size,
                              hipStream_t stream) {
  const float* feat = (const float*)d_in[0];
  const int* esrc   = (const int*)d_in[1];
  const int* edst   = (const int*)d_in[2];
  const int* qsrc   = (const int*)d_in[3];
  const int* qdst   = (const int*)d_in[4];
  const float* W1   = (const float*)d_in[5];
  const float* b1   = (const float*)d_in[6];
  const float* W2   = (const float*)d_in[7];
  const float* b2   = (const float*)d_in[8];
  float* out = (float*)d_out;

  const int N = in_sizes[0] / 128;
  const int E = in_sizes[1];
  const int Q = in_sizes[3];

  char* w = (char*)d_ws;
  size_t o = 0;
  float* X = (float*)(w + o);      o += align256((size_t)N * 128 * 4);
  float* H = (float*)(w + o);      o += align256((size_t)N * 128 * 4);
  int* cntOut = (int*)(w + o);     o += align256((size_t)N * 4);
  int* cntIn = (int*)(w + o);      o += align256((size_t)N * 4);
  float* normOut = (float*)(w + o); o += align256((size_t)N * 4);
  float* normIn = (float*)(w + o);  o += align256((size_t)N * 4);
  int* offs = (int*)(w + o);       o += align256((size_t)N * 4);
  int* cursor = (int*)(w + o);     o += align256((size_t)N * 4);
  int* bsums = (int*)(w + o);      o += align256((size_t)4096);
  int* csr = (int*)(w + o);        o += align256((size_t)E * 4);

  const int gE = (E + 255) / 256;
  const int gN = (N + 255) / 256;

  hipMemsetAsync(cntOut, 0, (size_t)N * 4, stream);
  hipMemsetAsync(cntIn, 0, (size_t)N * 4, stream);
  k_hist<<<gE, 256, 0, stream>>>(esrc, edst, cntOut, cntIn, E);
  k_norms<<<gN, 256, 0, stream>>>(cntOut, cntIn, normOut, normIn, N);
  k_scan1<<<gN, 256, 0, stream>>>(cntIn, offs, bsums, N);
  k_scan2<<<1, 512, 0, stream>>>(bsums, gN);
  k_scan3<<<gN, 256, 0, stream>>>(offs, bsums, cursor, N);
  k_scatter<<<gE, 256, 0, stream>>>(esrc, edst, cursor, csr, E);

  // layer 1: X1 = (feat*out_norm)@W1 ; H1 = relu(agg(X1)*in_norm + b1)
  k_gemm<128, 128><<<(N + 31) / 32, 256, 0, stream>>>(feat, normOut, W1, X, N);
  k_agg128_relu<<<(N + 3) / 4, 256, 0, stream>>>(X, csr, offs, cntIn, normIn, b1, H, N);
  // layer 2: X2 = (H1*out_norm)@W2 ; H2 = agg(X2)*in_norm + b2
  k_gemm<128, 64><<<(N + 31) / 32, 256, 0, stream>>>(H, normOut, W2, X, N);
  k_agg64<<<(N + 3) / 4, 256, 0, stream>>>(X, csr, offs, cntIn, normIn, b2, H, N);
  // scoring
  k_score<<<((Q * 16) + 255) / 256, 256, 0, stream>>>(H, qsrc, qdst, out, Q);
}

// Round 2
// 862.536 us; speedup vs baseline: 1.6716x; 1.6716x over previous
//
#include <hip/hip_runtime.h>
#include <math.h>

static inline size_t align256(size_t x) { return (x + 255) & ~(size_t)255; }

// ---------------- degree histogram ----------------
__global__ __launch_bounds__(256) void k_hist(const int* __restrict__ esrc,
                                              const int* __restrict__ edst,
                                              int* __restrict__ cntOut,
                                              int* __restrict__ cntIn, int E) {
  int i = blockIdx.x * 256 + threadIdx.x;
  if (i < E) {
    atomicAdd(&cntOut[esrc[i]], 1);
    atomicAdd(&cntIn[edst[i]], 1);
  }
}

__global__ __launch_bounds__(256) void k_norms(const int* __restrict__ cntOut,
                                               const int* __restrict__ cntIn,
                                               float* __restrict__ normOut,
                                               float* __restrict__ normIn, int n) {
  int i = blockIdx.x * 256 + threadIdx.x;
  if (i < n) {
    normOut[i] = rsqrtf((float)max(cntOut[i], 1));
    normIn[i]  = rsqrtf((float)max(cntIn[i], 1));
  }
}

// ---------------- exclusive scan (3-phase) ----------------
__global__ __launch_bounds__(256) void k_scan1(const int* __restrict__ in,
                                               int* __restrict__ out,
                                               int* __restrict__ bsums, int n) {
  __shared__ int s[256];
  int tid = threadIdx.x, gid = blockIdx.x * 256 + tid;
  int v = (gid < n) ? in[gid] : 0;
  s[tid] = v; __syncthreads();
  for (int o = 1; o < 256; o <<= 1) {
    int t = (tid >= o) ? s[tid - o] : 0;
    __syncthreads();
    s[tid] += t;
    __syncthreads();
  }
  if (gid < n) out[gid] = s[tid] - v;   // exclusive
  if (tid == 255) bsums[blockIdx.x] = s[255];
}

__global__ __launch_bounds__(512) void k_scan2(int* __restrict__ bsums, int nb) {
  __shared__ int s[512];
  int tid = threadIdx.x;
  int v = (tid < nb) ? bsums[tid] : 0;
  s[tid] = v; __syncthreads();
  for (int o = 1; o < 512; o <<= 1) {
    int t = (tid >= o) ? s[tid - o] : 0;
    __syncthreads();
    s[tid] += t;
    __syncthreads();
  }
  if (tid < nb) bsums[tid] = s[tid] - v;  // exclusive
}

__global__ __launch_bounds__(256) void k_scan3(int* __restrict__ offs,
                                               const int* __restrict__ bsums,
                                               int* __restrict__ cursor, int n) {
  int gid = blockIdx.x * 256 + threadIdx.x;
  if (gid < n) {
    int v = offs[gid] + bsums[blockIdx.x];
    offs[gid] = v;
    cursor[gid] = v;
  }
}

__global__ __launch_bounds__(256) void k_scatter(const int* __restrict__ esrc,
                                                 const int* __restrict__ edst,
                                                 int* __restrict__ cursor,
                                                 int* __restrict__ csr, int E) {
  int i = blockIdx.x * 256 + threadIdx.x;
  if (i < E) {
    int p = atomicAdd(&cursor[edst[i]], 1);
    csr[p] = esrc[i];
  }
}

// ---------------- scaled GEMM: out[n x C] = diag(scale) * A[n x K] @ W[K x C] ----------------
// 32 rows/block, K chunked by 64. Thread owns 4 cols x RPT rows; k stepped by 4
// with ds_read_b128 on both A and W. #pragma unroll 4 keeps VGPR pressure low
// (R1 post-mortem: full unroll + scalar ds_read -> 256 VGPR + 880 MB spill traffic).
template <int K, int C>
__global__ __launch_bounds__(256) void k_gemm(const float* __restrict__ A,
                                              const float* __restrict__ scale,
                                              const float* __restrict__ W,
                                              float* __restrict__ out, int n) {
  constexpr int ROWS = 32, KB = 64;
  constexpr int CG = C / 4;          // column groups of 4
  constexpr int RG = 256 / CG;       // row groups
  constexpr int RPT = ROWS / RG;     // rows per thread
  __shared__ __align__(16) float Wl[KB * C];
  __shared__ __align__(16) float Al[ROWS * KB];
  int tid = threadIdx.x;
  int r0 = blockIdx.x * ROWS;
  int cg = tid % CG, rg = tid / CG, c0 = cg * 4;
  float acc[RPT][4];
#pragma unroll
  for (int i = 0; i < RPT; ++i) { acc[i][0] = acc[i][1] = acc[i][2] = acc[i][3] = 0.f; }

  for (int kb = 0; kb < K; kb += KB) {
    for (int idx = tid; idx < KB * C; idx += 256)
      Wl[idx] = W[(size_t)kb * C + idx];
    for (int idx = tid; idx < ROWS * KB; idx += 256) {
      int row = idx / KB, k = idx % KB;
      int g = r0 + row;
      Al[idx] = (g < n) ? A[(size_t)g * K + kb + k] * scale[g] : 0.f;
    }
    __syncthreads();
#pragma unroll 4
    for (int k = 0; k < KB; k += 4) {
      float4 wv0 = *(const float4*)&Wl[(k + 0) * C + c0];
      float4 wv1 = *(const float4*)&Wl[(k + 1) * C + c0];
      float4 wv2 = *(const float4*)&Wl[(k + 2) * C + c0];
      float4 wv3 = *(const float4*)&Wl[(k + 3) * C + c0];
#pragma unroll
      for (int i = 0; i < RPT; ++i) {
        float4 av = *(const float4*)&Al[(rg + i * RG) * KB + k];
        acc[i][0] += av.x * wv0.x; acc[i][1] += av.x * wv0.y;
        acc[i][2] += av.x * wv0.z; acc[i][3] += av.x * wv0.w;
        acc[i][0] += av.y * wv1.x; acc[i][1] += av.y * wv1.y;
        acc[i][2] += av.y * wv1.z; acc[i][3] += av.y * wv1.w;
        acc[i][0] += av.z * wv2.x; acc[i][1] += av.z * wv2.y;
        acc[i][2] += av.z * wv2.z; acc[i][3] += av.z * wv2.w;
        acc[i][0] += av.w * wv3.x; acc[i][1] += av.w * wv3.y;
        acc[i][2] += av.w * wv3.z; acc[i][3] += av.w * wv3.w;
      }
    }
    __syncthreads();
  }
#pragma unroll
  for (int i = 0; i < RPT; ++i) {
    int g = r0 + rg + i * RG;
    if (g < n)
      *(float4*)&out[(size_t)g * C + c0] =
          make_float4(acc[i][0], acc[i][1], acc[i][2], acc[i][3]);
  }
}

// ---------------- aggregation: one wave per dst node ----------------
__global__ __launch_bounds__(256) void k_agg128_relu(const float* __restrict__ X,
                                                     const int* __restrict__ csr,
                                                     const int* __restrict__ offs,
                                                     const int* __restrict__ cnt,
                                                     const float* __restrict__ norm,
                                                     const float* __restrict__ bias,
                                                     float* __restrict__ H, int n) {
  int wid = blockIdx.x * 4 + (threadIdx.x >> 6);
  if (wid >= n) return;
  int lane = threadIdx.x & 63;
  int start = offs[wid], m = cnt[wid];
  float ax = 0.f, ay = 0.f;
  for (int e = 0; e < m; ++e) {
    int s = csr[start + e];
    float2 v = *(const float2*)(X + (size_t)s * 128 + lane * 2);
    ax += v.x; ay += v.y;
  }
  float nm = norm[wid];
  float2 b = *(const float2*)(bias + lane * 2);
  float ox = fmaxf(ax * nm + b.x, 0.f);
  float oy = fmaxf(ay * nm + b.y, 0.f);
  *(float2*)(H + (size_t)wid * 128 + lane * 2) = make_float2(ox, oy);
}

__global__ __launch_bounds__(256) void k_agg64(const float* __restrict__ X,
                                               const int* __restrict__ csr,
                                               const int* __restrict__ offs,
                                               const int* __restrict__ cnt,
                                               const float* __restrict__ norm,
                                               const float* __restrict__ bias,
                                               float* __restrict__ H, int n) {
  int wid = blockIdx.x * 4 + (threadIdx.x >> 6);
  if (wid >= n) return;
  int lane = threadIdx.x & 63;
  int start = offs[wid], m = cnt[wid];
  float a = 0.f;
  for (int e = 0; e < m; ++e) {
    int s = csr[start + e];
    a += X[(size_t)s * 64 + lane];
  }
  H[(size_t)wid * 64 + lane] = a * norm[wid] + bias[lane];
}

// ---------------- edge scoring: 16 lanes per query ----------------
__global__ __launch_bounds__(256) void k_score(const float* __restrict__ H,
                                               const int* __restrict__ qs,
                                               const int* __restrict__ qd,
                                               float* __restrict__ out, int q) {
  int t = blockIdx.x * 256 + threadIdx.x;
  int sub = t & 15;
  int q0 = t >> 4;
  float p = 0.f;
  if (q0 < q) {
    int s = qs[q0], d = qd[q0];
    float4 a = *(const float4*)(H + (size_t)s * 64 + sub * 4);
    float4 b = *(const float4*)(H + (size_t)d * 64 + sub * 4);
    p = a.x * b.x + a.y * b.y + a.z * b.z + a.w * b.w;
  }
  p += __shfl_xor(p, 1);
  p += __shfl_xor(p, 2);
  p += __shfl_xor(p, 4);
  p += __shfl_xor(p, 8);
  if (sub == 0 && q0 < q) out[q0] = 1.f / (1.f + expf(-p));
}

extern "C" void kernel_launch(void* const* d_in, const int* in_sizes, int n_in,
                              void* d_out, int out_size, void* d_ws, size_t ws_size,
                              hipStream_t stream) {
  const float* feat = (const float*)d_in[0];
  const int* esrc   = (const int*)d_in[1];
  const int* edst   = (const int*)d_in[2];
  const int* qsrc   = (const int*)d_in[3];
  const int* qdst   = (const int*)d_in[4];
  const float* W1   = (const float*)d_in[5];
  const float* b1   = (const float*)d_in[6];
  const float* W2   = (const float*)d_in[7];
  const float* b2   = (const float*)d_in[8];
  float* out = (float*)d_out;

  const int N = in_sizes[0] / 128;
  const int E = in_sizes[1];
  const int Q = in_sizes[3];

  char* w = (char*)d_ws;
  size_t o = 0;
  float* X = (float*)(w + o);      o += align256((size_t)N * 128 * 4);
  float* H = (float*)(w + o);      o += align256((size_t)N * 128 * 4);
  int* cntOut = (int*)(w + o);     o += align256((size_t)N * 4);
  int* cntIn = (int*)(w + o);      o += align256((size_t)N * 4);
  float* normOut = (float*)(w + o); o += align256((size_t)N * 4);
  float* normIn = (float*)(w + o);  o += align256((size_t)N * 4);
  int* offs = (int*)(w + o);       o += align256((size_t)N * 4);
  int* cursor = (int*)(w + o);     o += align256((size_t)N * 4);
  int* bsums = (int*)(w + o);      o += align256((size_t)4096);
  int* csr = (int*)(w + o);        o += align256((size_t)E * 4);

  const int gE = (E + 255) / 256;
  const int gN = (N + 255) / 256;

  hipMemsetAsync(cntOut, 0, (size_t)N * 4, stream);
  hipMemsetAsync(cntIn, 0, (size_t)N * 4, stream);
  k_hist<<<gE, 256, 0, stream>>>(esrc, edst, cntOut, cntIn, E);
  k_norms<<<gN, 256, 0, stream>>>(cntOut, cntIn, normOut, normIn, N);
  k_scan1<<<gN, 256, 0, stream>>>(cntIn, offs, bsums, N);
  k_scan2<<<1, 512, 0, stream>>>(bsums, gN);
  k_scan3<<<gN, 256, 0, stream>>>(offs, bsums, cursor, N);
  k_scatter<<<gE, 256, 0, stream>>>(esrc, edst, cursor, csr, E);

  // layer 1: X1 = (feat*out_norm)@W1 ; H1 = relu(agg(X1)*in_norm + b1)
  k_gemm<128, 128><<<(N + 31) / 32, 256, 0, stream>>>(feat, normOut, W1, X, N);
  k_agg128_relu<<<(N + 3) / 4, 256, 0, stream>>>(X, csr, offs, cntIn, normIn, b1, H, N);
  // layer 2: X2 = (H1*out_norm)@W2 ; H2 = agg(X2)*in_norm + b2
  k_gemm<128, 64><<<(N + 31) / 32, 256, 0, stream>>>(H, normOut, W2, X, N);
  k_agg64<<<(N + 3) / 4, 256, 0, stream>>>(X, csr, offs, cntIn, normIn, b2, H, N);
  // scoring
  k_score<<<((Q * 16) + 255) / 256, 256, 0, stream>>>(H, qsrc, qdst, out, Q);
}

// Round 3
// 644.029 us; speedup vs baseline: 2.2387x; 1.3393x over previous
//
#include <hip/hip_runtime.h>
#include <math.h>

static inline size_t align256(size_t x) { return (x + 255) & ~(size_t)255; }

// ---- bf16 helpers (fp32 accumulate everywhere; bf16 is storage only) ----
__device__ inline float bfLo(unsigned int u) {
  union { unsigned int i; float f; } v; v.i = u << 16; return v.f;
}
__device__ inline float bfHi(unsigned int u) {
  union { unsigned int i; float f; } v; v.i = u & 0xffff0000u; return v.f;
}
__device__ inline float bf2f(unsigned short u) {
  union { unsigned int i; float f; } v; v.i = ((unsigned int)u) << 16; return v.f;
}
__device__ inline unsigned short f2bf(float f) {
  union { float f; unsigned int i; } v; v.f = f;
  unsigned int r = v.i + 0x7FFF + ((v.i >> 16) & 1);  // RNE
  return (unsigned short)(r >> 16);
}

// ---------------- degree histogram ----------------
__global__ __launch_bounds__(256) void k_hist(const int* __restrict__ esrc,
                                              const int* __restrict__ edst,
                                              int* __restrict__ cntOut,
                                              int* __restrict__ cntIn, int E) {
  int i = blockIdx.x * 256 + threadIdx.x;
  if (i < E) {
    atomicAdd(&cntOut[esrc[i]], 1);
    atomicAdd(&cntIn[edst[i]], 1);
  }
}

__global__ __launch_bounds__(256) void k_norms(const int* __restrict__ cntOut,
                                               const int* __restrict__ cntIn,
                                               float* __restrict__ normOut,
                                               float* __restrict__ normIn, int n) {
  int i = blockIdx.x * 256 + threadIdx.x;
  if (i < n) {
    normOut[i] = rsqrtf((float)max(cntOut[i], 1));
    normIn[i]  = rsqrtf((float)max(cntIn[i], 1));
  }
}

// ---------------- exclusive scan (3-phase) ----------------
__global__ __launch_bounds__(256) void k_scan1(const int* __restrict__ in,
                                               int* __restrict__ out,
                                               int* __restrict__ bsums, int n) {
  __shared__ int s[256];
  int tid = threadIdx.x, gid = blockIdx.x * 256 + tid;
  int v = (gid < n) ? in[gid] : 0;
  s[tid] = v; __syncthreads();
  for (int o = 1; o < 256; o <<= 1) {
    int t = (tid >= o) ? s[tid - o] : 0;
    __syncthreads();
    s[tid] += t;
    __syncthreads();
  }
  if (gid < n) out[gid] = s[tid] - v;   // exclusive
  if (tid == 255) bsums[blockIdx.x] = s[255];
}

__global__ __launch_bounds__(512) void k_scan2(int* __restrict__ bsums, int nb) {
  __shared__ int s[512];
  int tid = threadIdx.x;
  int v = (tid < nb) ? bsums[tid] : 0;
  s[tid] = v; __syncthreads();
  for (int o = 1; o < 512; o <<= 1) {
    int t = (tid >= o) ? s[tid - o] : 0;
    __syncthreads();
    s[tid] += t;
    __syncthreads();
  }
  if (tid < nb) bsums[tid] = s[tid] - v;  // exclusive
}

__global__ __launch_bounds__(256) void k_scan3(int* __restrict__ offs,
                                               const int* __restrict__ bsums,
                                               int* __restrict__ cursor, int n) {
  int gid = blockIdx.x * 256 + threadIdx.x;
  if (gid < n) {
    int v = offs[gid] + bsums[blockIdx.x];
    offs[gid] = v;
    cursor[gid] = v;
  }
}

__global__ __launch_bounds__(256) void k_scatter(const int* __restrict__ esrc,
                                                 const int* __restrict__ edst,
                                                 int* __restrict__ cursor,
                                                 int* __restrict__ csr, int E) {
  int i = blockIdx.x * 256 + threadIdx.x;
  if (i < E) {
    int p = atomicAdd(&cursor[edst[i]], 1);
    csr[p] = esrc[i];
  }
}

// ---------------- scaled GEMM: out[n x C](bf16) = diag(scale) * A[n x K] @ W[K x C] ----------------
// TA = float (layer 1, feat) or unsigned short (layer 2, bf16 H1).
template <int K, int C, typename TA>
__global__ __launch_bounds__(256) void k_gemm(const TA* __restrict__ A,
                                              const float* __restrict__ scale,
                                              const float* __restrict__ W,
                                              unsigned short* __restrict__ out, int n) {
  constexpr int ROWS = 32, KB = 64;
  constexpr int CG = C / 4;          // column groups of 4
  constexpr int RG = 256 / CG;       // row groups
  constexpr int RPT = ROWS / RG;     // rows per thread
  __shared__ __align__(16) float Wl[KB * C];
  __shared__ __align__(16) float Al[ROWS * KB];
  int tid = threadIdx.x;
  int r0 = blockIdx.x * ROWS;
  int cg = tid % CG, rg = tid / CG, c0 = cg * 4;
  float acc[RPT][4];
#pragma unroll
  for (int i = 0; i < RPT; ++i) { acc[i][0] = acc[i][1] = acc[i][2] = acc[i][3] = 0.f; }

  for (int kb = 0; kb < K; kb += KB) {
    for (int idx = tid; idx < KB * C; idx += 256)
      Wl[idx] = W[(size_t)kb * C + idx];
    if constexpr (sizeof(TA) == 2) {
      for (int idx = tid; idx < ROWS * (KB / 2); idx += 256) {
        int row = idx / (KB / 2), kp = idx % (KB / 2);
        int g = r0 + row;
        float vx = 0.f, vy = 0.f;
        if (g < n) {
          unsigned int u = *(const unsigned int*)((const unsigned short*)A +
                                                  (size_t)g * K + kb + kp * 2);
          float sc = scale[g];
          vx = bfLo(u) * sc; vy = bfHi(u) * sc;
        }
        Al[row * KB + kp * 2] = vx;
        Al[row * KB + kp * 2 + 1] = vy;
      }
    } else {
      for (int idx = tid; idx < ROWS * KB; idx += 256) {
        int row = idx / KB, k = idx % KB;
        int g = r0 + row;
        Al[idx] = (g < n) ? (float)A[(size_t)g * K + kb + k] * scale[g] : 0.f;
      }
    }
    __syncthreads();
#pragma unroll 4
    for (int k = 0; k < KB; k += 4) {
      float4 wv0 = *(const float4*)&Wl[(k + 0) * C + c0];
      float4 wv1 = *(const float4*)&Wl[(k + 1) * C + c0];
      float4 wv2 = *(const float4*)&Wl[(k + 2) * C + c0];
      float4 wv3 = *(const float4*)&Wl[(k + 3) * C + c0];
#pragma unroll
      for (int i = 0; i < RPT; ++i) {
        float4 av = *(const float4*)&Al[(rg + i * RG) * KB + k];
        acc[i][0] += av.x * wv0.x; acc[i][1] += av.x * wv0.y;
        acc[i][2] += av.x * wv0.z; acc[i][3] += av.x * wv0.w;
        acc[i][0] += av.y * wv1.x; acc[i][1] += av.y * wv1.y;
        acc[i][2] += av.y * wv1.z; acc[i][3] += av.y * wv1.w;
        acc[i][0] += av.z * wv2.x; acc[i][1] += av.z * wv2.y;
        acc[i][2] += av.z * wv2.z; acc[i][3] += av.z * wv2.w;
        acc[i][0] += av.w * wv3.x; acc[i][1] += av.w * wv3.y;
        acc[i][2] += av.w * wv3.z; acc[i][3] += av.w * wv3.w;
      }
    }
    __syncthreads();
  }
#pragma unroll
  for (int i = 0; i < RPT; ++i) {
    int g = r0 + rg + i * RG;
    if (g < n) {
      ushort4 o;
      o.x = f2bf(acc[i][0]); o.y = f2bf(acc[i][1]);
      o.z = f2bf(acc[i][2]); o.w = f2bf(acc[i][3]);
      *(ushort4*)&out[(size_t)g * C + c0] = o;
    }
  }
}

// ---------------- aggregation (bf16 in/out, fp32 accumulate) ----------------
// one wave per dst node; lane covers 2 cols (uint = 2 bf16); edge loop unrolled 4x
// for MLP (R2 post-mortem: 13% VALU, 33% HBM -> latency-bound on 1 load in flight).
__global__ __launch_bounds__(256) void k_agg128_relu(const unsigned short* __restrict__ X,
                                                     const int* __restrict__ csr,
                                                     const int* __restrict__ offs,
                                                     const int* __restrict__ cnt,
                                                     const float* __restrict__ norm,
                                                     const float* __restrict__ bias,
                                                     unsigned short* __restrict__ H, int n) {
  int wid = blockIdx.x * 4 + (threadIdx.x >> 6);
  if (wid >= n) return;
  int lane = threadIdx.x & 63;
  int start = offs[wid], m = cnt[wid];
  const int* p = csr + start;
  const unsigned int* Xu = (const unsigned int*)X;  // row stride 64 uints
  float ax = 0.f, ay = 0.f;
  int e = 0;
  for (; e + 4 <= m; e += 4) {
    int s0 = p[e], s1 = p[e + 1], s2 = p[e + 2], s3 = p[e + 3];
    unsigned int u0 = Xu[(size_t)s0 * 64 + lane];
    unsigned int u1 = Xu[(size_t)s1 * 64 + lane];
    unsigned int u2 = Xu[(size_t)s2 * 64 + lane];
    unsigned int u3 = Xu[(size_t)s3 * 64 + lane];
    ax += bfLo(u0); ay += bfHi(u0);
    ax += bfLo(u1); ay += bfHi(u1);
    ax += bfLo(u2); ay += bfHi(u2);
    ax += bfLo(u3); ay += bfHi(u3);
  }
  for (; e < m; ++e) {
    unsigned int u = Xu[(size_t)p[e] * 64 + lane];
    ax += bfLo(u); ay += bfHi(u);
  }
  float nm = norm[wid];
  float bx = bias[lane * 2], by = bias[lane * 2 + 1];
  float ox = fmaxf(ax * nm + bx, 0.f);
  float oy = fmaxf(ay * nm + by, 0.f);
  unsigned int o = ((unsigned int)f2bf(oy) << 16) | f2bf(ox);
  ((unsigned int*)H)[(size_t)wid * 64 + lane] = o;
}

__global__ __launch_bounds__(256) void k_agg64(const unsigned short* __restrict__ X,
                                               const int* __restrict__ csr,
                                               const int* __restrict__ offs,
                                               const int* __restrict__ cnt,
                                               const float* __restrict__ norm,
                                               const float* __restrict__ bias,
                                               unsigned short* __restrict__ H, int n) {
  int wid = blockIdx.x * 4 + (threadIdx.x >> 6);
  if (wid >= n) return;
  int lane = threadIdx.x & 63;
  int start = offs[wid], m = cnt[wid];
  const int* p = csr + start;
  float a = 0.f;
  int e = 0;
  for (; e + 4 <= m; e += 4) {
    int s0 = p[e], s1 = p[e + 1], s2 = p[e + 2], s3 = p[e + 3];
    unsigned short u0 = X[(size_t)s0 * 64 + lane];
    unsigned short u1 = X[(size_t)s1 * 64 + lane];
    unsigned short u2 = X[(size_t)s2 * 64 + lane];
    unsigned short u3 = X[(size_t)s3 * 64 + lane];
    a += bf2f(u0) + bf2f(u1) + bf2f(u2) + bf2f(u3);
  }
  for (; e < m; ++e) a += bf2f(X[(size_t)p[e] * 64 + lane]);
  H[(size_t)wid * 64 + lane] = f2bf(a * norm[wid] + bias[lane]);
}

// ---------------- edge scoring: 16 lanes per query, bf16 rows ----------------
__global__ __launch_bounds__(256) void k_score(const unsigned short* __restrict__ H,
                                               const int* __restrict__ qs,
                                               const int* __restrict__ qd,
                                               float* __restrict__ out, int q) {
  int t = blockIdx.x * 256 + threadIdx.x;
  int sub = t & 15;
  int q0 = t >> 4;
  float p = 0.f;
  if (q0 < q) {
    int s = qs[q0], d = qd[q0];
    const uint2* Hu = (const uint2*)H;  // 4 bf16 per uint2, row stride 16 uint2
    uint2 a = Hu[(size_t)s * 16 + sub];
    uint2 b = Hu[(size_t)d * 16 + sub];
    p = bfLo(a.x) * bfLo(b.x) + bfHi(a.x) * bfHi(b.x) +
        bfLo(a.y) * bfLo(b.y) + bfHi(a.y) * bfHi(b.y);
  }
  p += __shfl_xor(p, 1);
  p += __shfl_xor(p, 2);
  p += __shfl_xor(p, 4);
  p += __shfl_xor(p, 8);
  if (sub == 0 && q0 < q) out[q0] = 1.f / (1.f + expf(-p));
}

extern "C" void kernel_launch(void* const* d_in, const int* in_sizes, int n_in,
                              void* d_out, int out_size, void* d_ws, size_t ws_size,
                              hipStream_t stream) {
  const float* feat = (const float*)d_in[0];
  const int* esrc   = (const int*)d_in[1];
  const int* edst   = (const int*)d_in[2];
  const int* qsrc   = (const int*)d_in[3];
  const int* qdst   = (const int*)d_in[4];
  const float* W1   = (const float*)d_in[5];
  const float* b1   = (const float*)d_in[6];
  const float* W2   = (const float*)d_in[7];
  const float* b2   = (const float*)d_in[8];
  float* out = (float*)d_out;

  const int N = in_sizes[0] / 128;
  const int E = in_sizes[1];
  const int Q = in_sizes[3];

  char* w = (char*)d_ws;
  size_t o = 0;
  unsigned short* X = (unsigned short*)(w + o); o += align256((size_t)N * 128 * 2);
  unsigned short* H = (unsigned short*)(w + o); o += align256((size_t)N * 128 * 2);
  int* cntOut = (int*)(w + o);      o += align256((size_t)N * 4);
  int* cntIn = (int*)(w + o);       o += align256((size_t)N * 4);
  float* normOut = (float*)(w + o); o += align256((size_t)N * 4);
  float* normIn = (float*)(w + o);  o += align256((size_t)N * 4);
  int* offs = (int*)(w + o);        o += align256((size_t)N * 4);
  int* cursor = (int*)(w + o);      o += align256((size_t)N * 4);
  int* bsums = (int*)(w + o);       o += align256((size_t)4096);
  int* csr = (int*)(w + o);         o += align256((size_t)E * 4);

  const int gE = (E + 255) / 256;
  const int gN = (N + 255) / 256;

  hipMemsetAsync(cntOut, 0, (size_t)N * 4, stream);
  hipMemsetAsync(cntIn, 0, (size_t)N * 4, stream);
  k_hist<<<gE, 256, 0, stream>>>(esrc, edst, cntOut, cntIn, E);
  k_norms<<<gN, 256, 0, stream>>>(cntOut, cntIn, normOut, normIn, N);
  k_scan1<<<gN, 256, 0, stream>>>(cntIn, offs, bsums, N);
  k_scan2<<<1, 512, 0, stream>>>(bsums, gN);
  k_scan3<<<gN, 256, 0, stream>>>(offs, bsums, cursor, N);
  k_scatter<<<gE, 256, 0, stream>>>(esrc, edst, cursor, csr, E);

  // layer 1: X1 = (feat*out_norm)@W1 ; H1 = relu(agg(X1)*in_norm + b1)   [bf16 X1,H1]
  k_gemm<128, 128, float><<<(N + 31) / 32, 256, 0, stream>>>(feat, normOut, W1, X, N);
  k_agg128_relu<<<(N + 3) / 4, 256, 0, stream>>>(X, csr, offs, cntIn, normIn, b1, H, N);
  // layer 2: X2 = (H1*out_norm)@W2 ; H2 = agg(X2)*in_norm + b2           [bf16 X2,H2]
  k_gemm<128, 64, unsigned short><<<(N + 31) / 32, 256, 0, stream>>>(H, normOut, W2, X, N);
  k_agg64<<<(N + 3) / 4, 256, 0, stream>>>(X, csr, offs, cntIn, normIn, b2, H, N);
  // scoring
  k_score<<<((Q * 16) + 255) / 256, 256, 0, stream>>>(H, qsrc, qdst, out, Q);
}

// Round 4
// 472.610 us; speedup vs baseline: 3.0507x; 1.3627x over previous
//
#include <hip/hip_runtime.h>
#include <math.h>

static inline size_t align256(size_t x) { return (x + 255) & ~(size_t)255; }

// ---- bf16 helpers (fp32 accumulate everywhere; bf16 is storage only) ----
__device__ inline float bfLo(unsigned int u) {
  union { unsigned int i; float f; } v; v.i = u << 16; return v.f;
}
__device__ inline float bfHi(unsigned int u) {
  union { unsigned int i; float f; } v; v.i = u & 0xffff0000u; return v.f;
}
__device__ inline float bf2f(unsigned short u) {
  union { unsigned int i; float f; } v; v.i = ((unsigned int)u) << 16; return v.f;
}
__device__ inline unsigned short f2bf(float f) {
  union { float f; unsigned int i; } v; v.f = f;
  unsigned int r = v.i + 0x7FFF + ((v.i >> 16) & 1);  // RNE
  return (unsigned short)(r >> 16);
}

// ============ graph build: two-level LDS-privatized binning ============
// R3 post-mortem: global atomicAdd write-through (32B/atomic at the coherence
// point) made k_hist/k_scatter 250 us. This build uses ONLY LDS atomics.
// Bucket b owns nodes [b*256, b*256+256); NB = ceil(N/256) <= 512.

// P1: per-block coarse histograms of dst and src keys.
__global__ __launch_bounds__(256) void k_coarse_count(const int* __restrict__ esrc,
                                                      const int* __restrict__ edst,
                                                      int E, int chunk, int NB, int G,
                                                      int* __restrict__ blkD,
                                                      int* __restrict__ blkS) {
  __shared__ int hD[512], hS[512];
  int blk = blockIdx.x, tid = threadIdx.x;
  for (int i = tid; i < NB; i += 256) { hD[i] = 0; hS[i] = 0; }
  __syncthreads();
  int s0 = blk * chunk, s1 = min(E, s0 + chunk);
  for (int e = s0 + tid; e < s1; e += 256) {
    atomicAdd(&hD[edst[e] >> 8], 1);
    atomicAdd(&hS[esrc[e] >> 8], 1);
  }
  __syncthreads();
  for (int i = tid; i < NB; i += 256) {     // bucket-major layout for the scan
    blkD[i * G + blk] = hD[i];
    blkS[i * G + blk] = hS[i];
  }
}

// 3-phase exclusive scan (len is a multiple of 256, len/256 <= 512)
__global__ __launch_bounds__(256) void k_scan1(const int* __restrict__ in,
                                               int* __restrict__ out,
                                               int* __restrict__ bsums, int n) {
  __shared__ int s[256];
  int tid = threadIdx.x, gid = blockIdx.x * 256 + tid;
  int v = (gid < n) ? in[gid] : 0;
  s[tid] = v; __syncthreads();
  for (int o = 1; o < 256; o <<= 1) {
    int t = (tid >= o) ? s[tid - o] : 0;
    __syncthreads();
    s[tid] += t;
    __syncthreads();
  }
  if (gid < n) out[gid] = s[tid] - v;   // exclusive
  if (tid == 255) bsums[blockIdx.x] = s[255];
}

__global__ __launch_bounds__(512) void k_scan2(int* __restrict__ bsums, int nb) {
  __shared__ int s[512];
  int tid = threadIdx.x;
  int v = (tid < nb) ? bsums[tid] : 0;
  s[tid] = v; __syncthreads();
  for (int o = 1; o < 512; o <<= 1) {
    int t = (tid >= o) ? s[tid - o] : 0;
    __syncthreads();
    s[tid] += t;
    __syncthreads();
  }
  if (tid < nb) bsums[tid] = s[tid] - v;  // exclusive
}

__global__ __launch_bounds__(256) void k_scan3b(int* __restrict__ arr,
                                                const int* __restrict__ bsums, int n) {
  int gid = blockIdx.x * 256 + threadIdx.x;
  if (gid < n) arr[gid] += bsums[blockIdx.x];
}

// P3: scatter (src,dst) pairs grouped by dst-bucket, src keys grouped by src-bucket.
__global__ __launch_bounds__(256) void k_coarse_scatter(const int* __restrict__ esrc,
                                                        const int* __restrict__ edst,
                                                        int E, int chunk, int NB, int G,
                                                        const int* __restrict__ scD,
                                                        const int* __restrict__ scS,
                                                        uint2* __restrict__ pairs,
                                                        unsigned int* __restrict__ keys) {
  __shared__ int cD[512], cS[512];
  int blk = blockIdx.x, tid = threadIdx.x;
  for (int i = tid; i < NB; i += 256) {
    cD[i] = scD[i * G + blk];
    cS[i] = scS[i * G + blk];
  }
  __syncthreads();
  int s0 = blk * chunk, s1 = min(E, s0 + chunk);
  for (int e = s0 + tid; e < s1; e += 256) {
    int s = esrc[e], d = edst[e];
    int pd = atomicAdd(&cD[d >> 8], 1);
    pairs[pd] = make_uint2((unsigned)s, (unsigned)d);
    int ps = atomicAdd(&cS[s >> 8], 1);
    keys[ps] = (unsigned)s;
  }
}

// P4d: per dst-bucket fine histogram + scan -> cntIn, normIn, offs, csr.
__global__ __launch_bounds__(256) void k_fine_dst(const uint2* __restrict__ pairs,
                                                  const int* __restrict__ scD,
                                                  int G, int E, int N, int NB,
                                                  int* __restrict__ cntIn,
                                                  float* __restrict__ normIn,
                                                  int* __restrict__ offs,
                                                  int* __restrict__ csr) {
  __shared__ int hist[256], scn[256], cur[256];
  int b = blockIdx.x, tid = threadIdx.x;
  int bstart = scD[b * G];
  int bend = (b + 1 < NB) ? scD[(b + 1) * G] : E;
  hist[tid] = 0;
  __syncthreads();
  for (int e = bstart + tid; e < bend; e += 256)
    atomicAdd(&hist[pairs[e].y & 255], 1);
  __syncthreads();
  int v = hist[tid];
  scn[tid] = v;
  __syncthreads();
  for (int o = 1; o < 256; o <<= 1) {
    int t = (tid >= o) ? scn[tid - o] : 0;
    __syncthreads();
    scn[tid] += t;
    __syncthreads();
  }
  int excl = scn[tid] - v;
  cur[tid] = excl;
  int node = b * 256 + tid;
  if (node < N) {
    cntIn[node] = v;
    normIn[node] = rsqrtf((float)max(v, 1));
    offs[node] = bstart + excl;
  }
  __syncthreads();
  for (int e = bstart + tid; e < bend; e += 256) {
    uint2 u = pairs[e];
    int p = bstart + atomicAdd(&cur[u.y & 255], 1);
    csr[p] = (int)u.x;
  }
}

// P4s: per src-bucket fine histogram -> normOut.
__global__ __launch_bounds__(256) void k_fine_src(const unsigned int* __restrict__ keys,
                                                  const int* __restrict__ scS,
                                                  int G, int E, int N, int NB,
                                                  float* __restrict__ normOut) {
  __shared__ int hist[256];
  int b = blockIdx.x, tid = threadIdx.x;
  int bstart = scS[b * G];
  int bend = (b + 1 < NB) ? scS[(b + 1) * G] : E;
  hist[tid] = 0;
  __syncthreads();
  for (int e = bstart + tid; e < bend; e += 256)
    atomicAdd(&hist[keys[e] & 255u], 1);
  __syncthreads();
  int node = b * 256 + tid;
  if (node < N) normOut[node] = rsqrtf((float)max(hist[tid], 1));
}

// ---------------- scaled GEMM: out[n x C](bf16) = diag(scale) * A[n x K] @ W[K x C] ----------------
template <int K, int C, typename TA>
__global__ __launch_bounds__(256) void k_gemm(const TA* __restrict__ A,
                                              const float* __restrict__ scale,
                                              const float* __restrict__ W,
                                              unsigned short* __restrict__ out, int n) {
  constexpr int ROWS = 32, KB = 64;
  constexpr int CG = C / 4;          // column groups of 4
  constexpr int RG = 256 / CG;       // row groups
  constexpr int RPT = ROWS / RG;     // rows per thread
  __shared__ __align__(16) float Wl[KB * C];
  __shared__ __align__(16) float Al[ROWS * KB];
  int tid = threadIdx.x;
  int r0 = blockIdx.x * ROWS;
  int cg = tid % CG, rg = tid / CG, c0 = cg * 4;
  float acc[RPT][4];
#pragma unroll
  for (int i = 0; i < RPT; ++i) { acc[i][0] = acc[i][1] = acc[i][2] = acc[i][3] = 0.f; }

  for (int kb = 0; kb < K; kb += KB) {
    for (int idx = tid; idx < KB * C; idx += 256)
      Wl[idx] = W[(size_t)kb * C + idx];
    if constexpr (sizeof(TA) == 2) {
      for (int idx = tid; idx < ROWS * (KB / 2); idx += 256) {
        int row = idx / (KB / 2), kp = idx % (KB / 2);
        int g = r0 + row;
        float vx = 0.f, vy = 0.f;
        if (g < n) {
          unsigned int u = *(const unsigned int*)((const unsigned short*)A +
                                                  (size_t)g * K + kb + kp * 2);
          float sc = scale[g];
          vx = bfLo(u) * sc; vy = bfHi(u) * sc;
        }
        Al[row * KB + kp * 2] = vx;
        Al[row * KB + kp * 2 + 1] = vy;
      }
    } else {
      for (int idx = tid; idx < ROWS * KB; idx += 256) {
        int row = idx / KB, k = idx % KB;
        int g = r0 + row;
        Al[idx] = (g < n) ? (float)A[(size_t)g * K + kb + k] * scale[g] : 0.f;
      }
    }
    __syncthreads();
#pragma unroll 4
    for (int k = 0; k < KB; k += 4) {
      float4 wv0 = *(const float4*)&Wl[(k + 0) * C + c0];
      float4 wv1 = *(const float4*)&Wl[(k + 1) * C + c0];
      float4 wv2 = *(const float4*)&Wl[(k + 2) * C + c0];
      float4 wv3 = *(const float4*)&Wl[(k + 3) * C + c0];
#pragma unroll
      for (int i = 0; i < RPT; ++i) {
        float4 av = *(const float4*)&Al[(rg + i * RG) * KB + k];
        acc[i][0] += av.x * wv0.x; acc[i][1] += av.x * wv0.y;
        acc[i][2] += av.x * wv0.z; acc[i][3] += av.x * wv0.w;
        acc[i][0] += av.y * wv1.x; acc[i][1] += av.y * wv1.y;
        acc[i][2] += av.y * wv1.z; acc[i][3] += av.y * wv1.w;
        acc[i][0] += av.z * wv2.x; acc[i][1] += av.z * wv2.y;
        acc[i][2] += av.z * wv2.z; acc[i][3] += av.z * wv2.w;
        acc[i][0] += av.w * wv3.x; acc[i][1] += av.w * wv3.y;
        acc[i][2] += av.w * wv3.z; acc[i][3] += av.w * wv3.w;
      }
    }
    __syncthreads();
  }
#pragma unroll
  for (int i = 0; i < RPT; ++i) {
    int g = r0 + rg + i * RG;
    if (g < n) {
      ushort4 o;
      o.x = f2bf(acc[i][0]); o.y = f2bf(acc[i][1]);
      o.z = f2bf(acc[i][2]); o.w = f2bf(acc[i][3]);
      *(ushort4*)&out[(size_t)g * C + c0] = o;
    }
  }
}

// ---------------- aggregation (bf16 in/out, fp32 accumulate) ----------------
__global__ __launch_bounds__(256) void k_agg128_relu(const unsigned short* __restrict__ X,
                                                     const int* __restrict__ csr,
                                                     const int* __restrict__ offs,
                                                     const int* __restrict__ cnt,
                                                     const float* __restrict__ norm,
                                                     const float* __restrict__ bias,
                                                     unsigned short* __restrict__ H, int n) {
  int wid = blockIdx.x * 4 + (threadIdx.x >> 6);
  if (wid >= n) return;
  int lane = threadIdx.x & 63;
  int start = offs[wid], m = cnt[wid];
  const int* p = csr + start;
  const unsigned int* Xu = (const unsigned int*)X;  // row stride 64 uints
  float ax = 0.f, ay = 0.f;
  int e = 0;
  for (; e + 4 <= m; e += 4) {
    int s0 = p[e], s1 = p[e + 1], s2 = p[e + 2], s3 = p[e + 3];
    unsigned int u0 = Xu[(size_t)s0 * 64 + lane];
    unsigned int u1 = Xu[(size_t)s1 * 64 + lane];
    unsigned int u2 = Xu[(size_t)s2 * 64 + lane];
    unsigned int u3 = Xu[(size_t)s3 * 64 + lane];
    ax += bfLo(u0); ay += bfHi(u0);
    ax += bfLo(u1); ay += bfHi(u1);
    ax += bfLo(u2); ay += bfHi(u2);
    ax += bfLo(u3); ay += bfHi(u3);
  }
  for (; e < m; ++e) {
    unsigned int u = Xu[(size_t)p[e] * 64 + lane];
    ax += bfLo(u); ay += bfHi(u);
  }
  float nm = norm[wid];
  float bx = bias[lane * 2], by = bias[lane * 2 + 1];
  float ox = fmaxf(ax * nm + bx, 0.f);
  float oy = fmaxf(ay * nm + by, 0.f);
  unsigned int o = ((unsigned int)f2bf(oy) << 16) | f2bf(ox);
  ((unsigned int*)H)[(size_t)wid * 64 + lane] = o;
}

__global__ __launch_bounds__(256) void k_agg64(const unsigned short* __restrict__ X,
                                               const int* __restrict__ csr,
                                               const int* __restrict__ offs,
                                               const int* __restrict__ cnt,
                                               const float* __restrict__ norm,
                                               const float* __restrict__ bias,
                                               unsigned short* __restrict__ H, int n) {
  int wid = blockIdx.x * 4 + (threadIdx.x >> 6);
  if (wid >= n) return;
  int lane = threadIdx.x & 63;
  int start = offs[wid], m = cnt[wid];
  const int* p = csr + start;
  float a = 0.f;
  int e = 0;
  for (; e + 4 <= m; e += 4) {
    int s0 = p[e], s1 = p[e + 1], s2 = p[e + 2], s3 = p[e + 3];
    unsigned short u0 = X[(size_t)s0 * 64 + lane];
    unsigned short u1 = X[(size_t)s1 * 64 + lane];
    unsigned short u2 = X[(size_t)s2 * 64 + lane];
    unsigned short u3 = X[(size_t)s3 * 64 + lane];
    a += bf2f(u0) + bf2f(u1) + bf2f(u2) + bf2f(u3);
  }
  for (; e < m; ++e) a += bf2f(X[(size_t)p[e] * 64 + lane]);
  H[(size_t)wid * 64 + lane] = f2bf(a * norm[wid] + bias[lane]);
}

// ---------------- edge scoring: 16 lanes per query, bf16 rows ----------------
__global__ __launch_bounds__(256) void k_score(const unsigned short* __restrict__ H,
                                               const int* __restrict__ qs,
                                               const int* __restrict__ qd,
                                               float* __restrict__ out, int q) {
  int t = blockIdx.x * 256 + threadIdx.x;
  int sub = t & 15;
  int q0 = t >> 4;
  float p = 0.f;
  if (q0 < q) {
    int s = qs[q0], d = qd[q0];
    const uint2* Hu = (const uint2*)H;  // 4 bf16 per uint2, row stride 16 uint2
    uint2 a = Hu[(size_t)s * 16 + sub];
    uint2 b = Hu[(size_t)d * 16 + sub];
    p = bfLo(a.x) * bfLo(b.x) + bfHi(a.x) * bfHi(b.x) +
        bfLo(a.y) * bfLo(b.y) + bfHi(a.y) * bfHi(b.y);
  }
  p += __shfl_xor(p, 1);
  p += __shfl_xor(p, 2);
  p += __shfl_xor(p, 4);
  p += __shfl_xor(p, 8);
  if (sub == 0 && q0 < q) out[q0] = 1.f / (1.f + expf(-p));
}

extern "C" void kernel_launch(void* const* d_in, const int* in_sizes, int n_in,
                              void* d_out, int out_size, void* d_ws, size_t ws_size,
                              hipStream_t stream) {
  const float* feat = (const float*)d_in[0];
  const int* esrc   = (const int*)d_in[1];
  const int* edst   = (const int*)d_in[2];
  const int* qsrc   = (const int*)d_in[3];
  const int* qdst   = (const int*)d_in[4];
  const float* W1   = (const float*)d_in[5];
  const float* b1   = (const float*)d_in[6];
  const float* W2   = (const float*)d_in[7];
  const float* b2   = (const float*)d_in[8];
  float* out = (float*)d_out;

  const int N = in_sizes[0] / 128;
  const int E = in_sizes[1];
  const int Q = in_sizes[3];

  const int G = 256;                       // coarse blocks
  const int NB = (N + 255) >> 8;           // coarse buckets (<=512 for N<=131072)
  const int chunk = (E + G - 1) / G;
  const int lenS = NB * G;                 // scan length (multiple of 256)
  const int gScan = lenS / 256;            // = NB <= 512

  char* w = (char*)d_ws;
  size_t o = 0;
  unsigned short* X = (unsigned short*)(w + o); o += align256((size_t)N * 128 * 2);
  unsigned short* H = (unsigned short*)(w + o); o += align256((size_t)N * 128 * 2);
  int* cntIn = (int*)(w + o);       o += align256((size_t)N * 4);
  float* normOut = (float*)(w + o); o += align256((size_t)N * 4);
  float* normIn = (float*)(w + o);  o += align256((size_t)N * 4);
  int* offs = (int*)(w + o);        o += align256((size_t)N * 4);
  int* blkD = (int*)(w + o);        o += align256((size_t)lenS * 4);
  int* blkS = (int*)(w + o);        o += align256((size_t)lenS * 4);
  int* scD = (int*)(w + o);         o += align256((size_t)lenS * 4);
  int* scS = (int*)(w + o);         o += align256((size_t)lenS * 4);
  int* bsums = (int*)(w + o);       o += align256((size_t)4096);
  uint2* pairs = (uint2*)(w + o);   o += align256((size_t)E * 8);
  unsigned int* keys = (unsigned int*)(w + o); o += align256((size_t)E * 4);
  int* csr = (int*)(w + o);         o += align256((size_t)E * 4);

  // graph build (no global atomics)
  k_coarse_count<<<G, 256, 0, stream>>>(esrc, edst, E, chunk, NB, G, blkD, blkS);
  k_scan1<<<gScan, 256, 0, stream>>>(blkD, scD, bsums, lenS);
  k_scan2<<<1, 512, 0, stream>>>(bsums, gScan);
  k_scan3b<<<gScan, 256, 0, stream>>>(scD, bsums, lenS);
  k_scan1<<<gScan, 256, 0, stream>>>(blkS, scS, bsums, lenS);
  k_scan2<<<1, 512, 0, stream>>>(bsums, gScan);
  k_scan3b<<<gScan, 256, 0, stream>>>(scS, bsums, lenS);
  k_coarse_scatter<<<G, 256, 0, stream>>>(esrc, edst, E, chunk, NB, G, scD, scS, pairs, keys);
  k_fine_dst<<<NB, 256, 0, stream>>>(pairs, scD, G, E, N, NB, cntIn, normIn, offs, csr);
  k_fine_src<<<NB, 256, 0, stream>>>(keys, scS, G, E, N, NB, normOut);

  // layer 1: X1 = (feat*out_norm)@W1 ; H1 = relu(agg(X1)*in_norm + b1)   [bf16 X1,H1]
  k_gemm<128, 128, float><<<(N + 31) / 32, 256, 0, stream>>>(feat, normOut, W1, X, N);
  k_agg128_relu<<<(N + 3) / 4, 256, 0, stream>>>(X, csr, offs, cntIn, normIn, b1, H, N);
  // layer 2: X2 = (H1*out_norm)@W2 ; H2 = agg(X2)*in_norm + b2           [bf16 X2,H2]
  k_gemm<128, 64, unsigned short><<<(N + 31) / 32, 256, 0, stream>>>(H, normOut, W2, X, N);
  k_agg64<<<(N + 3) / 4, 256, 0, stream>>>(X, csr, offs, cntIn, normIn, b2, H, N);
  // scoring
  k_score<<<((Q * 16) + 255) / 256, 256, 0, stream>>>(H, qsrc, qdst, out, Q);
}

// Round 5
// 395.236 us; speedup vs baseline: 3.6479x; 1.1958x over previous
//
#include <hip/hip_runtime.h>
#include <math.h>

static inline size_t align256(size_t x) { return (x + 255) & ~(size_t)255; }

typedef __attribute__((ext_vector_type(8))) short bf16x8;
typedef __attribute__((ext_vector_type(4))) float f32x4;

// ---- bf16 helpers (fp32 accumulate everywhere; bf16 is storage only) ----
__device__ inline float bfLo(unsigned int u) {
  union { unsigned int i; float f; } v; v.i = u << 16; return v.f;
}
__device__ inline float bfHi(unsigned int u) {
  union { unsigned int i; float f; } v; v.i = u & 0xffff0000u; return v.f;
}
__device__ inline float bf2f(unsigned short u) {
  union { unsigned int i; float f; } v; v.i = ((unsigned int)u) << 16; return v.f;
}
__device__ inline unsigned short f2bf(float f) {
  union { float f; unsigned int i; } v; v.f = f;
  unsigned int r = v.i + 0x7FFF + ((v.i >> 16) & 1);  // RNE
  return (unsigned short)(r >> 16);
}
__device__ inline unsigned int packbf(float lo, float hi) {
  return ((unsigned int)f2bf(hi) << 16) | f2bf(lo);
}

// ============ graph build: two-level LDS-privatized binning ============
__global__ __launch_bounds__(256) void k_coarse_count(const int* __restrict__ esrc,
                                                      const int* __restrict__ edst,
                                                      int E, int chunk, int NB, int G,
                                                      int* __restrict__ blkD,
                                                      int* __restrict__ blkS) {
  __shared__ int hD[512], hS[512];
  int blk = blockIdx.x, tid = threadIdx.x;
  for (int i = tid; i < NB; i += 256) { hD[i] = 0; hS[i] = 0; }
  __syncthreads();
  int s0 = blk * chunk, s1 = min(E, s0 + chunk);
  for (int e = s0 + tid; e < s1; e += 256) {
    atomicAdd(&hD[edst[e] >> 8], 1);
    atomicAdd(&hS[esrc[e] >> 8], 1);
  }
  __syncthreads();
  for (int i = tid; i < NB; i += 256) {
    blkD[i * G + blk] = hD[i];
    blkS[i * G + blk] = hS[i];
  }
}

__global__ __launch_bounds__(256) void k_scan1(const int* __restrict__ in,
                                               int* __restrict__ out,
                                               int* __restrict__ bsums, int n) {
  __shared__ int s[256];
  int tid = threadIdx.x, gid = blockIdx.x * 256 + tid;
  int v = (gid < n) ? in[gid] : 0;
  s[tid] = v; __syncthreads();
  for (int o = 1; o < 256; o <<= 1) {
    int t = (tid >= o) ? s[tid - o] : 0;
    __syncthreads();
    s[tid] += t;
    __syncthreads();
  }
  if (gid < n) out[gid] = s[tid] - v;
  if (tid == 255) bsums[blockIdx.x] = s[255];
}

__global__ __launch_bounds__(512) void k_scan2(int* __restrict__ bsums, int nb) {
  __shared__ int s[512];
  int tid = threadIdx.x;
  int v = (tid < nb) ? bsums[tid] : 0;
  s[tid] = v; __syncthreads();
  for (int o = 1; o < 512; o <<= 1) {
    int t = (tid >= o) ? s[tid - o] : 0;
    __syncthreads();
    s[tid] += t;
    __syncthreads();
  }
  if (tid < nb) bsums[tid] = s[tid] - v;
}

__global__ __launch_bounds__(256) void k_scan3b(int* __restrict__ arr,
                                                const int* __restrict__ bsums, int n) {
  int gid = blockIdx.x * 256 + threadIdx.x;
  if (gid < n) arr[gid] += bsums[blockIdx.x];
}

__global__ __launch_bounds__(256) void k_coarse_scatter(const int* __restrict__ esrc,
                                                        const int* __restrict__ edst,
                                                        int E, int chunk, int NB, int G,
                                                        const int* __restrict__ scD,
                                                        const int* __restrict__ scS,
                                                        uint2* __restrict__ pairs,
                                                        unsigned int* __restrict__ keys) {
  __shared__ int cD[512], cS[512];
  int blk = blockIdx.x, tid = threadIdx.x;
  for (int i = tid; i < NB; i += 256) {
    cD[i] = scD[i * G + blk];
    cS[i] = scS[i * G + blk];
  }
  __syncthreads();
  int s0 = blk * chunk, s1 = min(E, s0 + chunk);
  for (int e = s0 + tid; e < s1; e += 256) {
    int s = esrc[e], d = edst[e];
    int pd = atomicAdd(&cD[d >> 8], 1);
    pairs[pd] = make_uint2((unsigned)s, (unsigned)d);
    int ps = atomicAdd(&cS[s >> 8], 1);
    keys[ps] = (unsigned)s;
  }
}

__global__ __launch_bounds__(256) void k_fine_dst(const uint2* __restrict__ pairs,
                                                  const int* __restrict__ scD,
                                                  int G, int E, int N, int NB,
                                                  int* __restrict__ cntIn,
                                                  float* __restrict__ normIn,
                                                  int* __restrict__ offs,
                                                  int* __restrict__ csr) {
  __shared__ int hist[256], scn[256], cur[256];
  int b = blockIdx.x, tid = threadIdx.x;
  int bstart = scD[b * G];
  int bend = (b + 1 < NB) ? scD[(b + 1) * G] : E;
  hist[tid] = 0;
  __syncthreads();
  for (int e = bstart + tid; e < bend; e += 256)
    atomicAdd(&hist[pairs[e].y & 255], 1);
  __syncthreads();
  int v = hist[tid];
  scn[tid] = v;
  __syncthreads();
  for (int o = 1; o < 256; o <<= 1) {
    int t = (tid >= o) ? scn[tid - o] : 0;
    __syncthreads();
    scn[tid] += t;
    __syncthreads();
  }
  int excl = scn[tid] - v;
  cur[tid] = excl;
  int node = b * 256 + tid;
  if (node < N) {
    cntIn[node] = v;
    normIn[node] = rsqrtf((float)max(v, 1));
    offs[node] = bstart + excl;
  }
  __syncthreads();
  for (int e = bstart + tid; e < bend; e += 256) {
    uint2 u = pairs[e];
    int p = bstart + atomicAdd(&cur[u.y & 255], 1);
    csr[p] = (int)u.x;
  }
}

__global__ __launch_bounds__(256) void k_fine_src(const unsigned int* __restrict__ keys,
                                                  const int* __restrict__ scS,
                                                  int G, int E, int N, int NB,
                                                  float* __restrict__ normOut) {
  __shared__ int hist[256];
  int b = blockIdx.x, tid = threadIdx.x;
  int bstart = scS[b * G];
  int bend = (b + 1 < NB) ? scS[(b + 1) * G] : E;
  hist[tid] = 0;
  __syncthreads();
  for (int e = bstart + tid; e < bend; e += 256)
    atomicAdd(&hist[keys[e] & 255u], 1);
  __syncthreads();
  int node = b * 256 + tid;
  if (node < N) normOut[node] = rsqrtf((float)max(hist[tid], 1));
}

// ---------------- weight prep: W[K x C] fp32 -> Wt[C x K] bf16 (n-major) ----------------
__global__ __launch_bounds__(256) void k_prep(const float* __restrict__ W1,
                                              const float* __restrict__ W2,
                                              unsigned short* __restrict__ W1t,
                                              unsigned short* __restrict__ W2t) {
  int t = blockIdx.x * 256 + threadIdx.x;
  int stride = gridDim.x * 256;
  for (int i = t; i < 128 * 128; i += stride) {
    int nn = i >> 7, kk = i & 127;          // i = n*128 + k
    W1t[i] = f2bf(W1[kk * 128 + nn]);
  }
  for (int i = t; i < 64 * 128; i += stride) {
    int nn = i >> 7, kk = i & 127;
    W2t[i] = f2bf(W2[kk * 64 + nn]);
  }
}

// ---------------- MFMA GEMM: out[n x C](bf16) = diag(scale)*A[n x 128] @ W[128 x C] ----------------
// 64 rows/block (4 waves x 16 rows). A,Wt staged in LDS as bf16, k-stride padded
// to 136 (row-start banks spread 8-wide -> <=2-way conflict = free, m136).
// A-frag: A[m=lane&15][k=quad*8+j] (m120); B-frag: Wt[n=lane&15][k=quad*8+j];
// C/D: col=lane&15, row=quad*4+reg (m89).
template <int C, typename TA>
__global__ __launch_bounds__(256) void k_mgemm(const TA* __restrict__ A,
                                               const float* __restrict__ scale,
                                               const unsigned short* __restrict__ Wt,
                                               unsigned short* __restrict__ out, int n) {
  constexpr int KP = 136;            // padded k stride in bf16 units (272 B)
  constexpr int NCH = C / 16;        // column chunks
  __shared__ __align__(16) unsigned short Al[64 * KP];
  __shared__ __align__(16) unsigned short Wl[C * KP];
  int tid = threadIdx.x;
  int r0 = blockIdx.x * 64;

  // stage Wt -> LDS (uint4 = 8 bf16; global row = 16 uint4, LDS row = 17)
  {
    const uint4* Wg = (const uint4*)Wt;
    uint4* Wd = (uint4*)Wl;
    for (int idx = tid; idx < C * 16; idx += 256) {
      int row = idx >> 4, seg = idx & 15;
      Wd[row * 17 + seg] = Wg[idx];
    }
  }
  // stage A (scaled, bf16): 8 threads/row, each covers 16 cols; 32 rows/pass
  {
    int seg = tid & 7;
    for (int it = 0; it < 2; ++it) {
      int row = (tid >> 3) + it * 32;
      int g = r0 + row;
      float v[16];
      if (g < n) {
        float sc = scale[g];
        if constexpr (sizeof(TA) == 4) {
          const float4* Ag = (const float4*)((const float*)A + (size_t)g * 128);
#pragma unroll
          for (int j = 0; j < 4; ++j) {
            float4 f = Ag[seg * 4 + j];
            v[j * 4 + 0] = f.x * sc; v[j * 4 + 1] = f.y * sc;
            v[j * 4 + 2] = f.z * sc; v[j * 4 + 3] = f.w * sc;
          }
        } else {
          const uint4* Ag = (const uint4*)((const unsigned short*)A + (size_t)g * 128);
#pragma unroll
          for (int j = 0; j < 2; ++j) {
            uint4 u = Ag[seg * 2 + j];
            v[j * 8 + 0] = bfLo(u.x) * sc; v[j * 8 + 1] = bfHi(u.x) * sc;
            v[j * 8 + 2] = bfLo(u.y) * sc; v[j * 8 + 3] = bfHi(u.y) * sc;
            v[j * 8 + 4] = bfLo(u.z) * sc; v[j * 8 + 5] = bfHi(u.z) * sc;
            v[j * 8 + 6] = bfLo(u.w) * sc; v[j * 8 + 7] = bfHi(u.w) * sc;
          }
        }
      } else {
#pragma unroll
        for (int j = 0; j < 16; ++j) v[j] = 0.f;
      }
      uint4* dst = (uint4*)(Al + row * KP + seg * 16);
      dst[0] = make_uint4(packbf(v[0], v[1]), packbf(v[2], v[3]),
                          packbf(v[4], v[5]), packbf(v[6], v[7]));
      dst[1] = make_uint4(packbf(v[8], v[9]), packbf(v[10], v[11]),
                          packbf(v[12], v[13]), packbf(v[14], v[15]));
    }
  }
  __syncthreads();

  int lane = tid & 63;
  int w = tid >> 6;
  int quad = lane >> 4, m16 = lane & 15;
  f32x4 acc[NCH];
#pragma unroll
  for (int c = 0; c < NCH; ++c) acc[c] = (f32x4){0.f, 0.f, 0.f, 0.f};

#pragma unroll
  for (int kc = 0; kc < 4; ++kc) {
    int ko = kc * 32 + quad * 8;
    bf16x8 a = *(const bf16x8*)(Al + (w * 16 + m16) * KP + ko);
#pragma unroll
    for (int c = 0; c < NCH; ++c) {
      bf16x8 b = *(const bf16x8*)(Wl + (c * 16 + m16) * KP + ko);
      acc[c] = __builtin_amdgcn_mfma_f32_16x16x32_bf16(a, b, acc[c], 0, 0, 0);
    }
  }

#pragma unroll
  for (int c = 0; c < NCH; ++c)
#pragma unroll
    for (int r = 0; r < 4; ++r) {
      int g = r0 + w * 16 + quad * 4 + r;
      if (g < n) out[(size_t)g * C + c * 16 + m16] = f2bf(acc[c][r]);
    }
}

// ---------------- aggregation (bf16 in/out, fp32 accumulate) ----------------
__global__ __launch_bounds__(256) void k_agg128_relu(const unsigned short* __restrict__ X,
                                                     const int* __restrict__ csr,
                                                     const int* __restrict__ offs,
                                                     const int* __restrict__ cnt,
                                                     const float* __restrict__ norm,
                                                     const float* __restrict__ bias,
                                                     unsigned short* __restrict__ H, int n) {
  int wid = blockIdx.x * 4 + (threadIdx.x >> 6);
  if (wid >= n) return;
  int lane = threadIdx.x & 63;
  int start = offs[wid], m = cnt[wid];
  const int* p = csr + start;
  const unsigned int* Xu = (const unsigned int*)X;  // row stride 64 uints
  float ax = 0.f, ay = 0.f;
  int e = 0;
  for (; e + 4 <= m; e += 4) {
    int s0 = p[e], s1 = p[e + 1], s2 = p[e + 2], s3 = p[e + 3];
    unsigned int u0 = Xu[(size_t)s0 * 64 + lane];
    unsigned int u1 = Xu[(size_t)s1 * 64 + lane];
    unsigned int u2 = Xu[(size_t)s2 * 64 + lane];
    unsigned int u3 = Xu[(size_t)s3 * 64 + lane];
    ax += bfLo(u0); ay += bfHi(u0);
    ax += bfLo(u1); ay += bfHi(u1);
    ax += bfLo(u2); ay += bfHi(u2);
    ax += bfLo(u3); ay += bfHi(u3);
  }
  for (; e < m; ++e) {
    unsigned int u = Xu[(size_t)p[e] * 64 + lane];
    ax += bfLo(u); ay += bfHi(u);
  }
  float nm = norm[wid];
  float bx = bias[lane * 2], by = bias[lane * 2 + 1];
  float ox = fmaxf(ax * nm + bx, 0.f);
  float oy = fmaxf(ay * nm + by, 0.f);
  unsigned int o = ((unsigned int)f2bf(oy) << 16) | f2bf(ox);
  ((unsigned int*)H)[(size_t)wid * 64 + lane] = o;
}

__global__ __launch_bounds__(256) void k_agg64(const unsigned short* __restrict__ X,
                                               const int* __restrict__ csr,
                                               const int* __restrict__ offs,
                                               const int* __restrict__ cnt,
                                               const float* __restrict__ norm,
                                               const float* __restrict__ bias,
                                               unsigned short* __restrict__ H, int n) {
  int wid = blockIdx.x * 4 + (threadIdx.x >> 6);
  if (wid >= n) return;
  int lane = threadIdx.x & 63;
  int start = offs[wid], m = cnt[wid];
  const int* p = csr + start;
  float a = 0.f;
  int e = 0;
  for (; e + 4 <= m; e += 4) {
    int s0 = p[e], s1 = p[e + 1], s2 = p[e + 2], s3 = p[e + 3];
    unsigned short u0 = X[(size_t)s0 * 64 + lane];
    unsigned short u1 = X[(size_t)s1 * 64 + lane];
    unsigned short u2 = X[(size_t)s2 * 64 + lane];
    unsigned short u3 = X[(size_t)s3 * 64 + lane];
    a += bf2f(u0) + bf2f(u1) + bf2f(u2) + bf2f(u3);
  }
  for (; e < m; ++e) a += bf2f(X[(size_t)p[e] * 64 + lane]);
  H[(size_t)wid * 64 + lane] = f2bf(a * norm[wid] + bias[lane]);
}

// ---------------- edge scoring: 16 lanes per query, bf16 rows ----------------
__global__ __launch_bounds__(256) void k_score(const unsigned short* __restrict__ H,
                                               const int* __restrict__ qs,
                                               const int* __restrict__ qd,
                                               float* __restrict__ out, int q) {
  int t = blockIdx.x * 256 + threadIdx.x;
  int sub = t & 15;
  int q0 = t >> 4;
  float p = 0.f;
  if (q0 < q) {
    int s = qs[q0], d = qd[q0];
    const uint2* Hu = (const uint2*)H;
    uint2 a = Hu[(size_t)s * 16 + sub];
    uint2 b = Hu[(size_t)d * 16 + sub];
    p = bfLo(a.x) * bfLo(b.x) + bfHi(a.x) * bfHi(b.x) +
        bfLo(a.y) * bfLo(b.y) + bfHi(a.y) * bfHi(b.y);
  }
  p += __shfl_xor(p, 1);
  p += __shfl_xor(p, 2);
  p += __shfl_xor(p, 4);
  p += __shfl_xor(p, 8);
  if (sub == 0 && q0 < q) out[q0] = 1.f / (1.f + expf(-p));
}

extern "C" void kernel_launch(void* const* d_in, const int* in_sizes, int n_in,
                              void* d_out, int out_size, void* d_ws, size_t ws_size,
                              hipStream_t stream) {
  const float* feat = (const float*)d_in[0];
  const int* esrc   = (const int*)d_in[1];
  const int* edst   = (const int*)d_in[2];
  const int* qsrc   = (const int*)d_in[3];
  const int* qdst   = (const int*)d_in[4];
  const float* W1   = (const float*)d_in[5];
  const float* b1   = (const float*)d_in[6];
  const float* W2   = (const float*)d_in[7];
  const float* b2   = (const float*)d_in[8];
  float* out = (float*)d_out;

  const int N = in_sizes[0] / 128;
  const int E = in_sizes[1];
  const int Q = in_sizes[3];

  const int G = 256;
  const int NB = (N + 255) >> 8;
  const int chunk = (E + G - 1) / G;
  const int lenS = NB * G;
  const int gScan = lenS / 256;

  char* w = (char*)d_ws;
  size_t o = 0;
  unsigned short* X = (unsigned short*)(w + o); o += align256((size_t)N * 128 * 2);
  unsigned short* H = (unsigned short*)(w + o); o += align256((size_t)N * 128 * 2);
  int* cntIn = (int*)(w + o);       o += align256((size_t)N * 4);
  float* normOut = (float*)(w + o); o += align256((size_t)N * 4);
  float* normIn = (float*)(w + o);  o += align256((size_t)N * 4);
  int* offs = (int*)(w + o);        o += align256((size_t)N * 4);
  int* blkD = (int*)(w + o);        o += align256((size_t)lenS * 4);
  int* blkS = (int*)(w + o);        o += align256((size_t)lenS * 4);
  int* scD = (int*)(w + o);         o += align256((size_t)lenS * 4);
  int* scS = (int*)(w + o);         o += align256((size_t)lenS * 4);
  int* bsums = (int*)(w + o);       o += align256((size_t)4096);
  unsigned short* W1t = (unsigned short*)(w + o); o += align256((size_t)128 * 128 * 2);
  unsigned short* W2t = (unsigned short*)(w + o); o += align256((size_t)64 * 128 * 2);
  uint2* pairs = (uint2*)(w + o);   o += align256((size_t)E * 8);
  unsigned int* keys = (unsigned int*)(w + o); o += align256((size_t)E * 4);
  int* csr = (int*)(w + o);         o += align256((size_t)E * 4);

  // weight prep (bf16 transposed)
  k_prep<<<64, 256, 0, stream>>>(W1, W2, W1t, W2t);

  // graph build (no global atomics)
  k_coarse_count<<<G, 256, 0, stream>>>(esrc, edst, E, chunk, NB, G, blkD, blkS);
  k_scan1<<<gScan, 256, 0, stream>>>(blkD, scD, bsums, lenS);
  k_scan2<<<1, 512, 0, stream>>>(bsums, gScan);
  k_scan3b<<<gScan, 256, 0, stream>>>(scD, bsums, lenS);
  k_scan1<<<gScan, 256, 0, stream>>>(blkS, scS, bsums, lenS);
  k_scan2<<<1, 512, 0, stream>>>(bsums, gScan);
  k_scan3b<<<gScan, 256, 0, stream>>>(scS, bsums, lenS);
  k_coarse_scatter<<<G, 256, 0, stream>>>(esrc, edst, E, chunk, NB, G, scD, scS, pairs, keys);
  k_fine_dst<<<NB, 256, 0, stream>>>(pairs, scD, G, E, N, NB, cntIn, normIn, offs, csr);
  k_fine_src<<<NB, 256, 0, stream>>>(keys, scS, G, E, N, NB, normOut);

  const int gRows = (N + 63) / 64;
  // layer 1: X1 = (feat*out_norm)@W1 ; H1 = relu(agg(X1)*in_norm + b1)   [bf16]
  k_mgemm<128, float><<<gRows, 256, 0, stream>>>(feat, normOut, W1t, X, N);
  k_agg128_relu<<<(N + 3) / 4, 256, 0, stream>>>(X, csr, offs, cntIn, normIn, b1, H, N);
  // layer 2: X2 = (H1*out_norm)@W2 ; H2 = agg(X2)*in_norm + b2           [bf16]
  k_mgemm<64, unsigned short><<<gRows, 256, 0, stream>>>(H, normOut, W2t, X, N);
  k_agg64<<<(N + 3) / 4, 256, 0, stream>>>(X, csr, offs, cntIn, normIn, b2, H, N);
  // scoring
  k_score<<<((Q * 16) + 255) / 256, 256, 0, stream>>>(H, qsrc, qdst, out, Q);
}